// Round 2
// baseline (1032.577 us; speedup 1.0000x reference)
//
#include <hip/hip_runtime.h>
#include <hip/hip_bf16.h>
#include <stdint.h>

// ---------------------------------------------------------------------------
// StaticGNN: SAGEConv(mean) -> ReLU -> Linear -> ReLU -> SAGEConv(mean) ->
//            ReLU -> global_mean_pool -> fc
// Round 1: dtype-robust. Device probe detects float dtype (bf16 vs fp32) and
// int dtype (int32 vs int64); everything is converted to fp32 once, all
// compute kernels are fp32-only. CSR built once (hist/scan/scatter),
// gather-side mean aggregation (1 wave/node), LDS-tiled matmuls.
// ---------------------------------------------------------------------------

__device__ __forceinline__ float bits2f(uint32_t b) {
    union { uint32_t u; float f; } c; c.u = b; return c.f;
}

// ----- dtype probe --------------------------------------------------------
// flags[0]: 1 if float arrays are bf16, 0 if fp32
// flags[1]: 1 if int arrays are int64, 0 if int32
__global__ void probe_kernel(const unsigned short* __restrict__ x,
                             const int* __restrict__ ei,
                             int* __restrict__ flags) {
    __shared__ int cnt, orv;
    if (threadIdx.x == 0) { cnt = 0; orv = 0; }
    __syncthreads();
    unsigned short h = x[threadIdx.x];
    int e = (h >> 7) & 0xFF;
    if (e >= 102 && e <= 137) atomicAdd(&cnt, 1);
    if (threadIdx.x < 64) atomicOr(&orv, ei[2 * threadIdx.x + 1]);
    __syncthreads();
    if (threadIdx.x == 0) {
        flags[0] = (cnt >= 200) ? 1 : 0;
        flags[1] = (orv == 0) ? 1 : 0;
    }
}

// ----- convert x -> fp32 H (dual dtype) ----------------------------------
__global__ __launch_bounds__(256) void cvt_kernel(
    const void* __restrict__ x, float* __restrict__ H,
    const int* __restrict__ flags, int n8) {
    int i = blockIdx.x * 256 + threadIdx.x;
    if (i >= n8) return;
    float o[8];
    if (flags[0]) {
        uint4 u = ((const uint4*)x)[i];
        o[0] = bits2f(u.x << 16); o[1] = bits2f(u.x & 0xffff0000u);
        o[2] = bits2f(u.y << 16); o[3] = bits2f(u.y & 0xffff0000u);
        o[4] = bits2f(u.z << 16); o[5] = bits2f(u.z & 0xffff0000u);
        o[6] = bits2f(u.w << 16); o[7] = bits2f(u.w & 0xffff0000u);
    } else {
        float4 a = ((const float4*)x)[2 * i];
        float4 b = ((const float4*)x)[2 * i + 1];
        o[0] = a.x; o[1] = a.y; o[2] = a.z; o[3] = a.w;
        o[4] = b.x; o[5] = b.y; o[6] = b.z; o[7] = b.w;
    }
    float4* d = (float4*)(H + (size_t)i * 8);
    d[0] = make_float4(o[0], o[1], o[2], o[3]);
    d[1] = make_float4(o[4], o[5], o[6], o[7]);
}

// ----- weight conversion into contiguous fp32 region ---------------------
#define CW_W0L 0
#define CW_W0R 16384
#define CW_W1  32768
#define CW_W1L 49152
#define CW_W1R 65536
#define CW_FCW 81920
#define CW_B0L 82304
#define CW_B1  82432
#define CW_B1L 82560
#define CW_FCB 82688
#define CW_TOTAL 82691

__global__ __launch_bounds__(256) void wcvt_kernel(
    const void* s0, const void* s1, const void* s2, const void* s3,
    const void* s4, const void* s5, const void* s6, const void* s7,
    const void* s8, const void* s9,
    float* __restrict__ dst, const int* __restrict__ flags) {
    int i = blockIdx.x * 256 + threadIdx.x;
    if (i >= CW_TOTAL) return;
    const void* p; int k;
    if      (i < CW_W0R) { p = s0; k = i; }
    else if (i < CW_W1)  { p = s1; k = i - CW_W0R; }
    else if (i < CW_W1L) { p = s2; k = i - CW_W1; }
    else if (i < CW_W1R) { p = s3; k = i - CW_W1L; }
    else if (i < CW_FCW) { p = s4; k = i - CW_W1R; }
    else if (i < CW_B0L) { p = s5; k = i - CW_FCW; }
    else if (i < CW_B1)  { p = s6; k = i - CW_B0L; }
    else if (i < CW_B1L) { p = s7; k = i - CW_B1; }
    else if (i < CW_FCB) { p = s8; k = i - CW_B1L; }
    else                 { p = s9; k = i - CW_FCB; }
    float v = flags[0]
        ? bits2f((uint32_t)((const unsigned short*)p)[k] << 16)
        : ((const float*)p)[k];
    dst[i] = v;
}

// ----- degree histogram (dst rows) ---------------------------------------
__global__ __launch_bounds__(256) void hist_kernel(
    const int* __restrict__ ei, int* __restrict__ deg,
    const int* __restrict__ flags, int E) {
    int e = blockIdx.x * 256 + threadIdx.x;
    if (e >= E) return;
    int d = flags[1] ? ei[2 * (E + e)] : ei[E + e];
    atomicAdd(&deg[d], 1);
}

// ----- single-block exclusive scan (shuffle-based) -----------------------
__global__ __launch_bounds__(1024) void scan_kernel(
    const int* __restrict__ deg, int* __restrict__ rowptr,
    int* __restrict__ wcur, int n) {
    __shared__ int wsum[16];
    const int tid = threadIdx.x;
    const int lane = tid & 63, wid = tid >> 6;
    int running = 0;
    for (int base = 0; base < n; base += 4096) {
        int v[4]; int s = 0;
#pragma unroll
        for (int k = 0; k < 4; k++) {
            int i = base + tid * 4 + k;
            v[k] = (i < n) ? deg[i] : 0;
            s += v[k];
        }
        int sc = s;
#pragma unroll
        for (int off = 1; off < 64; off <<= 1) {
            int t = __shfl_up(sc, off, 64);
            if (lane >= off) sc += t;
        }
        if (lane == 63) wsum[wid] = sc;
        __syncthreads();
        int woff = 0, tot = 0;
        for (int w = 0; w < 16; w++) {
            int wv = wsum[w];
            tot += wv;
            if (w < wid) woff += wv;
        }
        int p = running + woff + (sc - s);   // exclusive prefix for v[0]
#pragma unroll
        for (int k = 0; k < 4; k++) {
            int i = base + tid * 4 + k;
            if (i < n) { rowptr[i] = p; wcur[i] = p; }
            p += v[k];
        }
        __syncthreads();
        running += tot;
    }
    if (tid == 0) rowptr[n] = running;
}

// ----- scatter src ids into CSR order ------------------------------------
__global__ __launch_bounds__(256) void scatter_kernel(
    const int* __restrict__ ei, int* __restrict__ wcur,
    int* __restrict__ nbr, const int* __restrict__ flags, int E) {
    int e = blockIdx.x * 256 + threadIdx.x;
    if (e >= E) return;
    int s, d;
    if (flags[1]) { s = ei[2 * e]; d = ei[2 * (E + e)]; }
    else          { s = ei[e];     d = ei[E + e]; }
    int pos = atomicAdd(&wcur[d], 1);
    nbr[pos] = s;
}

// ----- mean aggregation: A[n] = mean_{j in nbr(n)} H[j]  (1 wave/node) ---
__global__ __launch_bounds__(256) void aggr_kernel(
    const float* __restrict__ H, const int* __restrict__ rowptr,
    const int* __restrict__ nbr, float* __restrict__ Aout, int N) {
    int node = blockIdx.x * 4 + (threadIdx.x >> 6);
    int lane = threadIdx.x & 63;
    if (node >= N) return;
    int s = rowptr[node], e = rowptr[node + 1];
    float ax = 0.f, ay = 0.f;
    for (int it = s; it < e; ++it) {
        int jn = nbr[it];
        float2 v = *(const float2*)(H + (size_t)jn * 128 + lane * 2);
        ax += v.x; ay += v.y;
    }
    float inv = 1.f / fmaxf((float)(e - s), 1.f);
    *(float2*)(Aout + (size_t)node * 128 + lane * 2) = make_float2(ax * inv, ay * inv);
}

// ----- tiled matmul:  Y = relu( [A@Wl^T +] X@Wr^T + b ), in-place safe ---
template <bool HAS_A>
__global__ __launch_bounds__(256) void mm_kernel(
    const float* __restrict__ A, const float* __restrict__ X,
    const float* __restrict__ Wl, const float* __restrict__ Wr,
    const float* __restrict__ bias, float* __restrict__ Y) {
    __shared__ float As[16 * 128];
    __shared__ float Xs[16 * 128];
    const int t = threadIdx.x;
    const size_t row0 = (size_t)blockIdx.x * 16;

    {
        const float4* xsrc = (const float4*)(X + row0 * 128);
        float4* xdst = (float4*)Xs;
        xdst[t] = xsrc[t];
        xdst[t + 256] = xsrc[t + 256];
        if (HAS_A) {
            const float4* asrc = (const float4*)(A + row0 * 128);
            float4* adst = (float4*)As;
            adst[t] = asrc[t];
            adst[t + 256] = asrc[t + 256];
        }
    }
    __syncthreads();

    const int j = (t & 63) * 2;
    const int rg = t >> 6;
    float b0 = bias[j], b1 = bias[j + 1];
    float acc[4][2];
#pragma unroll
    for (int i = 0; i < 4; i++) { acc[i][0] = b0; acc[i][1] = b1; }

    const float4* wr0p = (const float4*)(Wr + (size_t)j * 128);
    const float4* wr1p = (const float4*)(Wr + (size_t)(j + 1) * 128);
    const float4* wl0p = HAS_A ? (const float4*)(Wl + (size_t)j * 128) : nullptr;
    const float4* wl1p = HAS_A ? (const float4*)(Wl + (size_t)(j + 1) * 128) : nullptr;

    for (int ki = 0; ki < 16; ki++) {
        float wr0[8], wr1[8], wl0[8], wl1[8];
        *(float4*)&wr0[0] = wr0p[2 * ki]; *(float4*)&wr0[4] = wr0p[2 * ki + 1];
        *(float4*)&wr1[0] = wr1p[2 * ki]; *(float4*)&wr1[4] = wr1p[2 * ki + 1];
        if (HAS_A) {
            *(float4*)&wl0[0] = wl0p[2 * ki]; *(float4*)&wl0[4] = wl0p[2 * ki + 1];
            *(float4*)&wl1[0] = wl1p[2 * ki]; *(float4*)&wl1[4] = wl1p[2 * ki + 1];
        }
#pragma unroll
        for (int i = 0; i < 4; i++) {
            const int n = rg + 4 * i;
            const float* xs = &Xs[n * 128 + ki * 8];
#pragma unroll
            for (int kk = 0; kk < 8; kk++) {
                float xv = xs[kk];
                acc[i][0] += xv * wr0[kk];
                acc[i][1] += xv * wr1[kk];
            }
            if (HAS_A) {
                const float* as_ = &As[n * 128 + ki * 8];
#pragma unroll
                for (int kk = 0; kk < 8; kk++) {
                    float av = as_[kk];
                    acc[i][0] += av * wl0[kk];
                    acc[i][1] += av * wl1[kk];
                }
            }
        }
    }
#pragma unroll
    for (int i = 0; i < 4; i++) {
        int n = rg + 4 * i;
        float2 v;
        v.x = fmaxf(acc[i][0], 0.f);
        v.y = fmaxf(acc[i][1], 0.f);
        *(float2*)(Y + (row0 + n) * 128 + j) = v;
    }
}

// ----- graph boundaries via binary search on sorted batch ----------------
__global__ void gstart_kernel(const int* __restrict__ batch,
                              int* __restrict__ gstart,
                              const int* __restrict__ flags, int N, int G) {
    int t = threadIdx.x;
    if (t > G) return;
    int f64 = flags[1];
    int lo = 0, hi = N;
    while (lo < hi) {
        int mid = (lo + hi) >> 1;
        int bv = f64 ? batch[2 * mid] : batch[mid];
        if (bv < t) lo = mid + 1; else hi = mid;
    }
    gstart[t] = lo;
}

// ----- pooled sums: run-length compressed atomics ------------------------
__global__ __launch_bounds__(256) void pool_kernel(
    const float* __restrict__ H, const int* __restrict__ batch,
    float* __restrict__ pool, const int* __restrict__ flags, int N) {
    int f = threadIdx.x & 127;
    int sub = threadIdx.x >> 7;
    int f64 = flags[1];
    int n0 = blockIdx.x * 64 + sub * 32;
    int gcur = -1;
    float s = 0.f;
    for (int i = 0; i < 32; i++) {
        int n = n0 + i;
        if (n >= N) break;
        int g = f64 ? batch[2 * n] : batch[n];
        float v = H[(size_t)n * 128 + f];
        if (g != gcur) {
            if (gcur >= 0) atomicAdd(&pool[gcur * 128 + f], s);
            gcur = g; s = v;
        } else {
            s += v;
        }
    }
    if (gcur >= 0) atomicAdd(&pool[gcur * 128 + f], s);
}

// ----- final fc: out[g,o] = (pool[g]/cnt) . fcW[o] + fcb[o] --------------
__global__ void fc_kernel(const float* __restrict__ pool,
                          const int* __restrict__ gstart,
                          const float* __restrict__ W,
                          const float* __restrict__ b,
                          void* __restrict__ out,
                          const int* __restrict__ flags, int G) {
    int t = threadIdx.x;
    if (t >= G * 3) return;
    int g = t / 3, o = t % 3;
    int cnt = gstart[g + 1] - gstart[g];
    float inv = 1.f / fmaxf((float)cnt, 1.f);
    float acc = 0.f;
    for (int k = 0; k < 128; k++)
        acc += pool[g * 128 + k] * W[o * 128 + k];
    float r = acc * inv + b[o];
    if (flags[0]) ((__hip_bfloat16*)out)[t] = __float2bfloat16(r);
    else          ((float*)out)[t] = r;
}

extern "C" void kernel_launch(void* const* d_in, const int* in_sizes, int n_in,
                              void* d_out, int out_size, void* d_ws, size_t ws_size,
                              hipStream_t stream) {
    const void* x   = d_in[0];
    const void* W0l = d_in[1];
    const void* b0l = d_in[2];
    const void* W0r = d_in[3];
    const void* W1  = d_in[4];
    const void* b1  = d_in[5];
    const void* W1l = d_in[6];
    const void* b1l = d_in[7];
    const void* W1r = d_in[8];
    const void* fcW = d_in[9];
    const void* fcb = d_in[10];
    const int* edge_index = (const int*)d_in[11];
    const int* batch      = (const int*)d_in[12];

    const int N = in_sizes[12];        // 50000
    const int E = in_sizes[11] / 2;    // 600000
    const int G = 32;

    char* ws = (char*)d_ws;
    auto align64 = [](size_t v) { return (v + 63) & ~(size_t)63; };
    size_t off = 0;
    size_t OFF_DEG  = off; off = align64(off + (size_t)N * 4);
    size_t OFF_POOL = off; off = align64(off + (size_t)G * 128 * 4);
    size_t MEMSET_BYTES = off;                  // deg + pool zeroed together
    size_t OFF_FLAGS = off; off = align64(off + 64);
    size_t OFF_GST  = off; off = align64(off + (size_t)(G + 1) * 4);
    size_t OFF_ROWP = off; off = align64(off + (size_t)(N + 1) * 4);
    size_t OFF_WCUR = off; off = align64(off + (size_t)N * 4);
    size_t OFF_NBR  = off; off = align64(off + (size_t)E * 4);
    size_t OFF_CW   = off; off = align64(off + (size_t)CW_TOTAL * 4);
    size_t OFF_A    = off; off = align64(off + (size_t)N * 128 * 4);
    size_t OFF_H    = off; off = align64(off + (size_t)N * 128 * 4);
    (void)ws_size;

    int*   deg    = (int*)(ws + OFF_DEG);
    float* pool   = (float*)(ws + OFF_POOL);
    int*   flags  = (int*)(ws + OFF_FLAGS);
    int*   gstart = (int*)(ws + OFF_GST);
    int*   rowptr = (int*)(ws + OFF_ROWP);
    int*   wcur   = (int*)(ws + OFF_WCUR);
    int*   nbr    = (int*)(ws + OFF_NBR);
    float* cw     = (float*)(ws + OFF_CW);
    float* Abuf   = (float*)(ws + OFF_A);
    float* Hbuf   = (float*)(ws + OFF_H);

    hipMemsetAsync(ws, 0, MEMSET_BYTES, stream);

    probe_kernel<<<1, 256, 0, stream>>>((const unsigned short*)x, edge_index, flags);

    int n8 = (N * 128) / 8;
    cvt_kernel<<<(n8 + 255) / 256, 256, 0, stream>>>(x, Hbuf, flags, n8);
    wcvt_kernel<<<(CW_TOTAL + 255) / 256, 256, 0, stream>>>(
        W0l, W0r, W1, W1l, W1r, fcW, b0l, b1, b1l, fcb, cw, flags);

    int egrid = (E + 255) / 256;
    hist_kernel<<<egrid, 256, 0, stream>>>(edge_index, deg, flags, E);
    scan_kernel<<<1, 1024, 0, stream>>>(deg, rowptr, wcur, N);
    scatter_kernel<<<egrid, 256, 0, stream>>>(edge_index, wcur, nbr, flags, E);

    int ngrid4 = (N + 3) / 4;
    int mmgrid = (N + 15) / 16;

    // conv0
    aggr_kernel<<<ngrid4, 256, 0, stream>>>(Hbuf, rowptr, nbr, Abuf, N);
    mm_kernel<true><<<mmgrid, 256, 0, stream>>>(Abuf, Hbuf,
        cw + CW_W0L, cw + CW_W0R, cw + CW_B0L, Hbuf);

    // lin1
    mm_kernel<false><<<mmgrid, 256, 0, stream>>>(nullptr, Hbuf,
        nullptr, cw + CW_W1, cw + CW_B1, Hbuf);

    // conv1
    aggr_kernel<<<ngrid4, 256, 0, stream>>>(Hbuf, rowptr, nbr, Abuf, N);
    mm_kernel<true><<<mmgrid, 256, 0, stream>>>(Abuf, Hbuf,
        cw + CW_W1L, cw + CW_W1R, cw + CW_B1L, Hbuf);

    // pooling + fc
    gstart_kernel<<<1, 64, 0, stream>>>(batch, gstart, flags, N, G);
    pool_kernel<<<(N + 63) / 64, 256, 0, stream>>>(Hbuf, batch, pool, flags, N);
    fc_kernel<<<1, 128, 0, stream>>>(pool, gstart, cw + CW_FCW, cw + CW_FCB,
                                     d_out, flags, G);

    (void)in_sizes; (void)n_in; (void)out_size;
}

// Round 3
// 440.842 us; speedup vs baseline: 2.3423x; 2.3423x over previous
//
#include <hip/hip_runtime.h>
#include <hip/hip_bf16.h>
#include <stdint.h>

// ---------------------------------------------------------------------------
// StaticGNN: SAGEConv(mean) -> ReLU -> Linear -> ReLU -> SAGEConv(mean) ->
//            ReLU -> global_mean_pool -> fc
// Round 3: matmuls moved to v_mfma_f32_16x16x32_bf16 (bf16 operands straight
// from global, 16B/lane frag loads; fp32 accum; LDS transpose epilogue for
// coalesced bf16 stores). H / aggregation buffers are bf16 (halves gather
// traffic). CSR build + dtype probe unchanged from the passing round-2 code.
// ---------------------------------------------------------------------------

typedef __attribute__((ext_vector_type(8))) short short8;
typedef __attribute__((ext_vector_type(4))) float f32x4;

__device__ __forceinline__ float bits2f(uint32_t b) {
    union { uint32_t u; float f; } c; c.u = b; return c.f;
}
__device__ __forceinline__ unsigned short f2bf(float f) {
    __hip_bfloat16 h = __float2bfloat16(f);
    union { __hip_bfloat16 h; unsigned short u; } c; c.h = h; return c.u;
}
__device__ __forceinline__ uint32_t pack2bf(float a, float b) {
    return (uint32_t)f2bf(a) | ((uint32_t)f2bf(b) << 16);
}

// ----- dtype probe --------------------------------------------------------
// flags[0]: 1 if float arrays are bf16, 0 if fp32
// flags[1]: 1 if int arrays are int64, 0 if int32
__global__ void probe_kernel(const unsigned short* __restrict__ x,
                             const int* __restrict__ ei,
                             int* __restrict__ flags) {
    __shared__ int cnt, orv;
    if (threadIdx.x == 0) { cnt = 0; orv = 0; }
    __syncthreads();
    unsigned short h = x[threadIdx.x];
    int e = (h >> 7) & 0xFF;
    if (e >= 102 && e <= 137) atomicAdd(&cnt, 1);
    if (threadIdx.x < 64) atomicOr(&orv, ei[2 * threadIdx.x + 1]);
    __syncthreads();
    if (threadIdx.x == 0) {
        flags[0] = (cnt >= 200) ? 1 : 0;
        flags[1] = (orv == 0) ? 1 : 0;
    }
}

// ----- convert x -> bf16 Hb ----------------------------------------------
__global__ __launch_bounds__(256) void cvt_kernel(
    const void* __restrict__ x, unsigned short* __restrict__ Hb,
    const int* __restrict__ flags, int n8) {
    int i = blockIdx.x * 256 + threadIdx.x;
    if (i >= n8) return;
    uint4 d;
    if (flags[0]) {
        d = ((const uint4*)x)[i];
    } else {
        float4 a = ((const float4*)x)[2 * i];
        float4 b = ((const float4*)x)[2 * i + 1];
        d.x = pack2bf(a.x, a.y); d.y = pack2bf(a.z, a.w);
        d.z = pack2bf(b.x, b.y); d.w = pack2bf(b.z, b.w);
    }
    ((uint4*)Hb)[i] = d;
}

// ----- weight conversion: 5 matrices -> bf16 wb --------------------------
#define WB_W0L 0
#define WB_W0R 16384
#define WB_W1  32768
#define WB_W1L 49152
#define WB_W1R 65536
#define WB_TOTAL 81920

__global__ __launch_bounds__(256) void wcvtb_kernel(
    const void* s0, const void* s1, const void* s2, const void* s3,
    const void* s4, unsigned short* __restrict__ dst,
    const int* __restrict__ flags) {
    int i = blockIdx.x * 256 + threadIdx.x;
    if (i >= WB_TOTAL) return;
    const void* p; int k = i & 16383;
    switch (i >> 14) {
        case 0: p = s0; break;
        case 1: p = s1; break;
        case 2: p = s2; break;
        case 3: p = s3; break;
        default: p = s4; break;
    }
    dst[i] = flags[0] ? ((const unsigned short*)p)[k]
                      : f2bf(((const float*)p)[k]);
}

// ----- biases + fc weights -> fp32 cw ------------------------------------
#define CF_B0L 0
#define CF_B1  128
#define CF_B1L 256
#define CF_FCW 384
#define CF_FCB 768
#define CF_TOTAL 771

__global__ void wcvtf_kernel(
    const void* s0, const void* s1, const void* s2, const void* s3,
    const void* s4, float* __restrict__ dst, const int* __restrict__ flags) {
    int i = blockIdx.x * 256 + threadIdx.x;
    if (i >= CF_TOTAL) return;
    const void* p; int k;
    if      (i < CF_B1)  { p = s0; k = i; }
    else if (i < CF_B1L) { p = s1; k = i - CF_B1; }
    else if (i < CF_FCW) { p = s2; k = i - CF_B1L; }
    else if (i < CF_FCB) { p = s3; k = i - CF_FCW; }
    else                 { p = s4; k = i - CF_FCB; }
    dst[i] = flags[0] ? bits2f((uint32_t)((const unsigned short*)p)[k] << 16)
                      : ((const float*)p)[k];
}

// ----- degree histogram (dst rows) ---------------------------------------
__global__ __launch_bounds__(256) void hist_kernel(
    const int* __restrict__ ei, int* __restrict__ deg,
    const int* __restrict__ flags, int E) {
    int e = blockIdx.x * 256 + threadIdx.x;
    if (e >= E) return;
    int d = flags[1] ? ei[2 * (E + e)] : ei[E + e];
    atomicAdd(&deg[d], 1);
}

// ----- single-block exclusive scan (shuffle-based) -----------------------
__global__ __launch_bounds__(1024) void scan_kernel(
    const int* __restrict__ deg, int* __restrict__ rowptr,
    int* __restrict__ wcur, int n) {
    __shared__ int wsum[16];
    const int tid = threadIdx.x;
    const int lane = tid & 63, wid = tid >> 6;
    int running = 0;
    for (int base = 0; base < n; base += 4096) {
        int v[4]; int s = 0;
#pragma unroll
        for (int k = 0; k < 4; k++) {
            int i = base + tid * 4 + k;
            v[k] = (i < n) ? deg[i] : 0;
            s += v[k];
        }
        int sc = s;
#pragma unroll
        for (int off = 1; off < 64; off <<= 1) {
            int t = __shfl_up(sc, off, 64);
            if (lane >= off) sc += t;
        }
        if (lane == 63) wsum[wid] = sc;
        __syncthreads();
        int woff = 0, tot = 0;
        for (int w = 0; w < 16; w++) {
            int wv = wsum[w];
            tot += wv;
            if (w < wid) woff += wv;
        }
        int p = running + woff + (sc - s);
#pragma unroll
        for (int k = 0; k < 4; k++) {
            int i = base + tid * 4 + k;
            if (i < n) { rowptr[i] = p; wcur[i] = p; }
            p += v[k];
        }
        __syncthreads();
        running += tot;
    }
    if (tid == 0) rowptr[n] = running;
}

// ----- scatter src ids into CSR order ------------------------------------
__global__ __launch_bounds__(256) void scatter_kernel(
    const int* __restrict__ ei, int* __restrict__ wcur,
    int* __restrict__ nbr, const int* __restrict__ flags, int E) {
    int e = blockIdx.x * 256 + threadIdx.x;
    if (e >= E) return;
    int s, d;
    if (flags[1]) { s = ei[2 * e]; d = ei[2 * (E + e)]; }
    else          { s = ei[e];     d = ei[E + e]; }
    int pos = atomicAdd(&wcur[d], 1);
    nbr[pos] = s;
}

// ----- mean aggregation over bf16 H -> bf16 A (1 wave/node) --------------
__global__ __launch_bounds__(256) void aggr_kernel(
    const unsigned short* __restrict__ Hb, const int* __restrict__ rowptr,
    const int* __restrict__ nbr, unsigned short* __restrict__ Ab, int N) {
    int node = blockIdx.x * 4 + (threadIdx.x >> 6);
    int lane = threadIdx.x & 63;
    if (node >= N) return;
    int s = rowptr[node], e = rowptr[node + 1];
    float ax = 0.f, ay = 0.f;
    for (int it = s; it < e; ++it) {
        int jn = nbr[it];
        uint32_t v = *(const uint32_t*)(Hb + (size_t)jn * 128 + lane * 2);
        ax += bits2f(v << 16);
        ay += bits2f(v & 0xffff0000u);
    }
    float inv = 1.f / fmaxf((float)(e - s), 1.f);
    *(uint32_t*)(Ab + (size_t)node * 128 + lane * 2) = pack2bf(ax * inv, ay * inv);
}

// ----- MFMA matmul: Y = relu( [A@Wl^T +] X@Wr^T + b ), bf16 in/out -------
// block = 256 thr (4 waves); 64 rows/block, 16 rows/wave; full N=128 cols.
template <bool HAS_A>
__global__ __launch_bounds__(256) void mmx_kernel(
    const unsigned short* __restrict__ Ab, const unsigned short* __restrict__ Xb,
    const unsigned short* __restrict__ Wl, const unsigned short* __restrict__ Wr,
    const float* __restrict__ bias, unsigned short* __restrict__ Y, int N) {
    __shared__ unsigned short obuf[4][16 * 128];
    const int t = threadIdx.x;
    const int lane = t & 63;
    const int w = t >> 6;
    const int m0 = blockIdx.x * 64 + w * 16;
    const int l15 = lane & 15;            // A-row / B-col / C-col
    const int kq = lane >> 4;             // k-quad 0..3

    f32x4 acc[8];
#pragma unroll
    for (int nt = 0; nt < 8; nt++) acc[nt] = (f32x4){0.f, 0.f, 0.f, 0.f};
    float bcol[8];
#pragma unroll
    for (int nt = 0; nt < 8; nt++) bcol[nt] = bias[nt * 16 + l15];

    const unsigned short* xrow = Xb + (size_t)(m0 + l15) * 128 + kq * 8;
    const unsigned short* arow = HAS_A ? (Ab + (size_t)(m0 + l15) * 128 + kq * 8) : nullptr;

#pragma unroll
    for (int kc = 0; kc < 4; kc++) {
        const int k0 = kc * 32;
        short8 axf = *(const short8*)(xrow + k0);
        short8 agf;
        if (HAS_A) agf = *(const short8*)(arow + k0);
#pragma unroll
        for (int nt = 0; nt < 8; nt++) {
            const size_t woff = (size_t)(nt * 16 + l15) * 128 + k0 + kq * 8;
            short8 br = *(const short8*)(Wr + woff);
            acc[nt] = __builtin_amdgcn_mfma_f32_16x16x32_bf16(axf, br, acc[nt], 0, 0, 0);
            if (HAS_A) {
                short8 bl = *(const short8*)(Wl + woff);
                acc[nt] = __builtin_amdgcn_mfma_f32_16x16x32_bf16(agf, bl, acc[nt], 0, 0, 0);
            }
        }
    }

    // epilogue: bias + relu + bf16, transpose via per-wave LDS (no barrier)
    unsigned short* ob = obuf[w];
#pragma unroll
    for (int nt = 0; nt < 8; nt++) {
#pragma unroll
        for (int r = 0; r < 4; r++) {
            float v = fmaxf(acc[nt][r] + bcol[nt], 0.f);
            int row = kq * 4 + r;          // C row = (lane>>4)*4 + reg
            int col = nt * 16 + l15;       // C col = lane&15
            ob[row * 128 + col] = f2bf(v);
        }
    }
#pragma unroll
    for (int p = 0; p < 4; p++) {
        int idx = p * 512 + lane * 8;
        int row = idx >> 7, col = idx & 127;
        int gm = m0 + row;
        if (gm < N)
            *(uint4*)(Y + (size_t)gm * 128 + col) = *(const uint4*)(ob + idx);
    }
}

// ----- graph boundaries via binary search on sorted batch ----------------
__global__ void gstart_kernel(const int* __restrict__ batch,
                              int* __restrict__ gstart,
                              const int* __restrict__ flags, int N, int G) {
    int t = threadIdx.x;
    if (t > G) return;
    int f64 = flags[1];
    int lo = 0, hi = N;
    while (lo < hi) {
        int mid = (lo + hi) >> 1;
        int bv = f64 ? batch[2 * mid] : batch[mid];
        if (bv < t) lo = mid + 1; else hi = mid;
    }
    gstart[t] = lo;
}

// ----- pooled sums: run-length compressed atomics (bf16 H) ---------------
__global__ __launch_bounds__(256) void pool_kernel(
    const unsigned short* __restrict__ Hb, const int* __restrict__ batch,
    float* __restrict__ pool, const int* __restrict__ flags, int N) {
    int f = threadIdx.x & 127;
    int sub = threadIdx.x >> 7;
    int f64 = flags[1];
    int n0 = blockIdx.x * 64 + sub * 32;
    int gcur = -1;
    float s = 0.f;
    for (int i = 0; i < 32; i++) {
        int n = n0 + i;
        if (n >= N) break;
        int g = f64 ? batch[2 * n] : batch[n];
        float v = bits2f((uint32_t)Hb[(size_t)n * 128 + f] << 16);
        if (g != gcur) {
            if (gcur >= 0) atomicAdd(&pool[gcur * 128 + f], s);
            gcur = g; s = v;
        } else {
            s += v;
        }
    }
    if (gcur >= 0) atomicAdd(&pool[gcur * 128 + f], s);
}

// ----- final fc ----------------------------------------------------------
__global__ void fc_kernel(const float* __restrict__ pool,
                          const int* __restrict__ gstart,
                          const float* __restrict__ W,
                          const float* __restrict__ b,
                          void* __restrict__ out,
                          const int* __restrict__ flags, int G) {
    int t = threadIdx.x;
    if (t >= G * 3) return;
    int g = t / 3, o = t % 3;
    int cnt = gstart[g + 1] - gstart[g];
    float inv = 1.f / fmaxf((float)cnt, 1.f);
    float acc = 0.f;
    for (int k = 0; k < 128; k++)
        acc += pool[g * 128 + k] * W[o * 128 + k];
    float r = acc * inv + b[o];
    if (flags[0]) ((__hip_bfloat16*)out)[t] = __float2bfloat16(r);
    else          ((float*)out)[t] = r;
}

extern "C" void kernel_launch(void* const* d_in, const int* in_sizes, int n_in,
                              void* d_out, int out_size, void* d_ws, size_t ws_size,
                              hipStream_t stream) {
    const void* x   = d_in[0];
    const void* W0l = d_in[1];
    const void* b0l = d_in[2];
    const void* W0r = d_in[3];
    const void* W1  = d_in[4];
    const void* b1  = d_in[5];
    const void* W1l = d_in[6];
    const void* b1l = d_in[7];
    const void* W1r = d_in[8];
    const void* fcW = d_in[9];
    const void* fcb = d_in[10];
    const int* edge_index = (const int*)d_in[11];
    const int* batch      = (const int*)d_in[12];

    const int N = in_sizes[12];        // 50000
    const int E = in_sizes[11] / 2;    // 600000
    const int G = 32;

    char* ws = (char*)d_ws;
    auto align64 = [](size_t v) { return (v + 63) & ~(size_t)63; };
    size_t off = 0;
    size_t OFF_DEG  = off; off = align64(off + (size_t)N * 4);
    size_t OFF_POOL = off; off = align64(off + (size_t)G * 128 * 4);
    size_t MEMSET_BYTES = off;                  // deg + pool zeroed together
    size_t OFF_FLAGS = off; off = align64(off + 64);
    size_t OFF_GST  = off; off = align64(off + (size_t)(G + 1) * 4);
    size_t OFF_ROWP = off; off = align64(off + (size_t)(N + 1) * 4);
    size_t OFF_WCUR = off; off = align64(off + (size_t)N * 4);
    size_t OFF_NBR  = off; off = align64(off + (size_t)E * 4);
    size_t OFF_WB   = off; off = align64(off + (size_t)WB_TOTAL * 2);
    size_t OFF_CF   = off; off = align64(off + (size_t)CF_TOTAL * 4);
    // +64 rows slack: MFMA tail block reads past row N
    size_t OFF_AB   = off; off = align64(off + ((size_t)N + 64) * 128 * 2);
    size_t OFF_HB   = off; off = align64(off + ((size_t)N + 64) * 128 * 2);
    (void)ws_size;

    int*    deg    = (int*)(ws + OFF_DEG);
    float*  pool   = (float*)(ws + OFF_POOL);
    int*    flags  = (int*)(ws + OFF_FLAGS);
    int*    gstart = (int*)(ws + OFF_GST);
    int*    rowptr = (int*)(ws + OFF_ROWP);
    int*    wcur   = (int*)(ws + OFF_WCUR);
    int*    nbr    = (int*)(ws + OFF_NBR);
    unsigned short* wb = (unsigned short*)(ws + OFF_WB);
    float*  cf     = (float*)(ws + OFF_CF);
    unsigned short* Abuf = (unsigned short*)(ws + OFF_AB);
    unsigned short* Hbuf = (unsigned short*)(ws + OFF_HB);

    hipMemsetAsync(ws, 0, MEMSET_BYTES, stream);

    probe_kernel<<<1, 256, 0, stream>>>((const unsigned short*)x, edge_index, flags);

    int n8 = (N * 128) / 8;
    cvt_kernel<<<(n8 + 255) / 256, 256, 0, stream>>>(x, Hbuf, flags, n8);
    wcvtb_kernel<<<(WB_TOTAL + 255) / 256, 256, 0, stream>>>(
        W0l, W0r, W1, W1l, W1r, wb, flags);
    wcvtf_kernel<<<(CF_TOTAL + 255) / 256, 256, 0, stream>>>(
        b0l, b1, b1l, fcW, fcb, cf, flags);

    int egrid = (E + 255) / 256;
    hist_kernel<<<egrid, 256, 0, stream>>>(edge_index, deg, flags, E);
    scan_kernel<<<1, 1024, 0, stream>>>(deg, rowptr, wcur, N);
    scatter_kernel<<<egrid, 256, 0, stream>>>(edge_index, wcur, nbr, flags, E);

    int ngrid4 = (N + 3) / 4;
    int mmgrid = (N + 63) / 64;

    // conv0: A = mean-gather(H);  H = relu(A@W0l^T + H@W0r^T + b0l)  (in-place)
    aggr_kernel<<<ngrid4, 256, 0, stream>>>(Hbuf, rowptr, nbr, Abuf, N);
    mmx_kernel<true><<<mmgrid, 256, 0, stream>>>(Abuf, Hbuf,
        wb + WB_W0L, wb + WB_W0R, cf + CF_B0L, Hbuf, N);

    // lin1: H = relu(H@W1^T + b1)
    mmx_kernel<false><<<mmgrid, 256, 0, stream>>>(nullptr, Hbuf,
        nullptr, wb + WB_W1, cf + CF_B1, Hbuf, N);

    // conv1
    aggr_kernel<<<ngrid4, 256, 0, stream>>>(Hbuf, rowptr, nbr, Abuf, N);
    mmx_kernel<true><<<mmgrid, 256, 0, stream>>>(Abuf, Hbuf,
        wb + WB_W1L, wb + WB_W1R, cf + CF_B1L, Hbuf, N);

    // pooling + fc
    gstart_kernel<<<1, 64, 0, stream>>>(batch, gstart, flags, N, G);
    pool_kernel<<<(N + 63) / 64, 256, 0, stream>>>(Hbuf, batch, pool, flags, N);
    fc_kernel<<<1, 128, 0, stream>>>(pool, gstart, cf + CF_FCW, cf + CF_FCB,
                                     d_out, flags, G);

    (void)in_sizes; (void)n_in; (void)out_size;
}

// Round 4
// 397.267 us; speedup vs baseline: 2.5992x; 1.1097x over previous
//
#include <hip/hip_runtime.h>
#include <hip/hip_bf16.h>
#include <stdint.h>

// ---------------------------------------------------------------------------
// StaticGNN: SAGEConv(mean) -> ReLU -> Linear -> ReLU -> SAGEConv(mean) ->
//            ReLU -> global_mean_pool -> fc
// Round 4: fused conv kernels. Per 64-node block: MLP-unrolled neighbor
// gather (shfl-broadcast indices, 4 loads in flight) -> MFMA conv -> (fused
// lin1 via swizzled LDS transpose) -> store h2 ... second kernel fuses conv1
// with segment pooling (no H store). 10 dispatches total.
// ---------------------------------------------------------------------------

typedef __attribute__((ext_vector_type(8))) short short8;
typedef __attribute__((ext_vector_type(4))) float f32x4;

__device__ __forceinline__ float bits2f(uint32_t b) {
    union { uint32_t u; float f; } c; c.u = b; return c.f;
}
__device__ __forceinline__ unsigned short f2bf(float f) {
    __hip_bfloat16 h = __float2bfloat16(f);
    union { __hip_bfloat16 h; unsigned short u; } c; c.h = h; return c.u;
}
__device__ __forceinline__ uint32_t pack2bf(float a, float b) {
    return (uint32_t)f2bf(a) | ((uint32_t)f2bf(b) << 16);
}

// ----- dtype probe --------------------------------------------------------
// flags[0]: 1 if float arrays are bf16, 0 if fp32
// flags[1]: 1 if int arrays are int64, 0 if int32
__global__ void probe_kernel(const unsigned short* __restrict__ x,
                             const int* __restrict__ ei,
                             int* __restrict__ flags) {
    __shared__ int cnt, orv;
    if (threadIdx.x == 0) { cnt = 0; orv = 0; }
    __syncthreads();
    unsigned short h = x[threadIdx.x];
    int e = (h >> 7) & 0xFF;
    if (e >= 102 && e <= 137) atomicAdd(&cnt, 1);
    if (threadIdx.x < 64) atomicOr(&orv, ei[2 * threadIdx.x + 1]);
    __syncthreads();
    if (threadIdx.x == 0) {
        flags[0] = (cnt >= 200) ? 1 : 0;
        flags[1] = (orv == 0) ? 1 : 0;
    }
}

// ----- convert x -> bf16 Hb ----------------------------------------------
__global__ __launch_bounds__(256) void cvt_kernel(
    const void* __restrict__ x, unsigned short* __restrict__ Hb,
    const int* __restrict__ flags, int n8) {
    int i = blockIdx.x * 256 + threadIdx.x;
    if (i >= n8) return;
    uint4 d;
    if (flags[0]) {
        d = ((const uint4*)x)[i];
    } else {
        float4 a = ((const float4*)x)[2 * i];
        float4 b = ((const float4*)x)[2 * i + 1];
        d.x = pack2bf(a.x, a.y); d.y = pack2bf(a.z, a.w);
        d.z = pack2bf(b.x, b.y); d.w = pack2bf(b.z, b.w);
    }
    ((uint4*)Hb)[i] = d;
}

// ----- weight conversion (bf16 mats + fp32 biases/fc) in one kernel ------
#define WB_W0L 0
#define WB_W0R 16384
#define WB_W1  32768
#define WB_W1L 49152
#define WB_W1R 65536
#define WB_TOTAL 81920
#define CF_B0L 0
#define CF_B1  128
#define CF_B1L 256
#define CF_FCW 384
#define CF_FCB 768
#define CF_TOTAL 771

__global__ __launch_bounds__(256) void wcvt_kernel(
    const void* s0, const void* s1, const void* s2, const void* s3,
    const void* s4, const void* f0, const void* f1, const void* f2,
    const void* f3, const void* f4,
    unsigned short* __restrict__ wb, float* __restrict__ cf,
    const int* __restrict__ flags) {
    int i = blockIdx.x * 256 + threadIdx.x;
    int isbf = flags[0];
    if (i < WB_TOTAL) {
        const void* p; int k = i & 16383;
        switch (i >> 14) {
            case 0: p = s0; break;
            case 1: p = s1; break;
            case 2: p = s2; break;
            case 3: p = s3; break;
            default: p = s4; break;
        }
        wb[i] = isbf ? ((const unsigned short*)p)[k]
                     : f2bf(((const float*)p)[k]);
    } else {
        int j = i - WB_TOTAL;
        if (j >= CF_TOTAL) return;
        const void* p; int k;
        if      (j < CF_B1)  { p = f0; k = j; }
        else if (j < CF_B1L) { p = f1; k = j - CF_B1; }
        else if (j < CF_FCW) { p = f2; k = j - CF_B1L; }
        else if (j < CF_FCB) { p = f3; k = j - CF_FCW; }
        else                 { p = f4; k = j - CF_FCB; }
        cf[j] = isbf ? bits2f((uint32_t)((const unsigned short*)p)[k] << 16)
                     : ((const float*)p)[k];
    }
}

// ----- degree histogram (dst rows) ---------------------------------------
__global__ __launch_bounds__(256) void hist_kernel(
    const int* __restrict__ ei, int* __restrict__ deg,
    const int* __restrict__ flags, int E) {
    int e = blockIdx.x * 256 + threadIdx.x;
    if (e >= E) return;
    int d = flags[1] ? ei[2 * (E + e)] : ei[E + e];
    atomicAdd(&deg[d], 1);
}

// ----- single-block exclusive scan (shuffle-based) -----------------------
__global__ __launch_bounds__(1024) void scan_kernel(
    const int* __restrict__ deg, int* __restrict__ rowptr,
    int* __restrict__ wcur, int n) {
    __shared__ int wsum[16];
    const int tid = threadIdx.x;
    const int lane = tid & 63, wid = tid >> 6;
    int running = 0;
    for (int base = 0; base < n; base += 4096) {
        int v[4]; int s = 0;
#pragma unroll
        for (int k = 0; k < 4; k++) {
            int i = base + tid * 4 + k;
            v[k] = (i < n) ? deg[i] : 0;
            s += v[k];
        }
        int sc = s;
#pragma unroll
        for (int off = 1; off < 64; off <<= 1) {
            int t = __shfl_up(sc, off, 64);
            if (lane >= off) sc += t;
        }
        if (lane == 63) wsum[wid] = sc;
        __syncthreads();
        int woff = 0, tot = 0;
        for (int w = 0; w < 16; w++) {
            int wv = wsum[w];
            tot += wv;
            if (w < wid) woff += wv;
        }
        int p = running + woff + (sc - s);
#pragma unroll
        for (int k = 0; k < 4; k++) {
            int i = base + tid * 4 + k;
            if (i < n) { rowptr[i] = p; wcur[i] = p; }
            p += v[k];
        }
        __syncthreads();
        running += tot;
    }
    if (tid == 0) rowptr[n] = running;
}

// ----- scatter src ids into CSR order ------------------------------------
__global__ __launch_bounds__(256) void scatter_kernel(
    const int* __restrict__ ei, int* __restrict__ wcur,
    int* __restrict__ nbr, const int* __restrict__ flags, int E) {
    int e = blockIdx.x * 256 + threadIdx.x;
    if (e >= E) return;
    int s, d;
    if (flags[1]) { s = ei[2 * e]; d = ei[2 * (E + e)]; }
    else          { s = ei[e];     d = ei[E + e]; }
    int pos = atomicAdd(&wcur[d], 1);
    nbr[pos] = s;
}

// ----- fused conv kernel -------------------------------------------------
// Per block: 64 nodes (16/wave). Phase1: MLP-unrolled gather-mean -> LDS.
// Phase2: MFMA (Wl on aggregate, Wr on self). If LIN1: ReLU -> swizzled LDS
// -> second MFMA with W2. If POOL: fused segment pooling (no store); else
// ReLU -> swizzled LDS -> coalesced bf16 store.
template <bool LIN1, bool POOL>
__global__ __launch_bounds__(256) void conv_kernel(
    const unsigned short* __restrict__ Hsrc,
    const int* __restrict__ rowptr, const int* __restrict__ nbr,
    const unsigned short* __restrict__ Wl, const unsigned short* __restrict__ Wr,
    const float* __restrict__ bias,
    const unsigned short* __restrict__ W2, const float* __restrict__ bias2,
    unsigned short* __restrict__ Hdst,
    float* __restrict__ pool, const int* __restrict__ batch,
    const int* __restrict__ flags, int N) {
    __shared__ unsigned short bufA[4][2048];   // 16 rows x 128 per wave
    __shared__ float pbuf[1024];               // 8 segs x 128 (POOL only)
    const int t = threadIdx.x;
    const int lane = t & 63;
    const int w = t >> 6;
    const int l15 = lane & 15;
    const int kq = lane >> 4;
    const int m0 = blockIdx.x * 64;
    const int mw = m0 + w * 16;

    int f64 = 0, gmin = 0;
    if (POOL) {
        f64 = flags[1];
        gmin = f64 ? batch[2 * m0] : batch[m0];
        for (int i = t; i < 1024; i += 256) pbuf[i] = 0.f;
        __syncthreads();
    }

    // ---- phase 1: gather-mean 16 rows into bufA[w] (row-major bf16)
    unsigned short* mybuf = bufA[w];
    const uint32_t* Hw = (const uint32_t*)Hsrc;
    for (int i = 0; i < 16; i++) {
        int node = mw + i;
        uint32_t outw = 0;
        if (node < N) {
            int s = rowptr[node], e = rowptr[node + 1];
            float ax = 0.f, ay = 0.f;
            for (int base = s; base < e; base += 64) {
                int cnt = e - base; if (cnt > 64) cnt = 64;
                int idx = (lane < cnt) ? nbr[base + lane] : 0;
                int it = 0;
                for (; it + 4 <= cnt; it += 4) {
                    int j0 = __shfl(idx, it, 64);
                    int j1 = __shfl(idx, it + 1, 64);
                    int j2 = __shfl(idx, it + 2, 64);
                    int j3 = __shfl(idx, it + 3, 64);
                    uint32_t v0 = Hw[(size_t)j0 * 64 + lane];
                    uint32_t v1 = Hw[(size_t)j1 * 64 + lane];
                    uint32_t v2 = Hw[(size_t)j2 * 64 + lane];
                    uint32_t v3 = Hw[(size_t)j3 * 64 + lane];
                    ax += bits2f(v0 << 16) + bits2f(v1 << 16)
                        + bits2f(v2 << 16) + bits2f(v3 << 16);
                    ay += bits2f(v0 & 0xffff0000u) + bits2f(v1 & 0xffff0000u)
                        + bits2f(v2 & 0xffff0000u) + bits2f(v3 & 0xffff0000u);
                }
                for (; it < cnt; ++it) {
                    int j = __shfl(idx, it, 64);
                    uint32_t v = Hw[(size_t)j * 64 + lane];
                    ax += bits2f(v << 16);
                    ay += bits2f(v & 0xffff0000u);
                }
            }
            float inv = 1.f / fmaxf((float)(e - s), 1.f);
            outw = pack2bf(ax * inv, ay * inv);
        }
        *(uint32_t*)(mybuf + i * 128 + lane * 2) = outw;
    }

    // ---- phase 2: matmul1  acc = agg@Wl^T + x@Wr^T
    f32x4 acc[8];
#pragma unroll
    for (int nt = 0; nt < 8; nt++) acc[nt] = (f32x4){0.f, 0.f, 0.f, 0.f};
    float bcol[8];
#pragma unroll
    for (int nt = 0; nt < 8; nt++) bcol[nt] = bias[nt * 16 + l15];

    short8 af[4], xf[4];
    {
        const unsigned short* xrow = Hsrc + (size_t)(mw + l15) * 128 + kq * 8;
#pragma unroll
        for (int kc = 0; kc < 4; kc++) {
            af[kc] = *(const short8*)(mybuf + l15 * 128 + kc * 32 + kq * 8);
            xf[kc] = *(const short8*)(xrow + kc * 32);
        }
    }
#pragma unroll
    for (int kc = 0; kc < 4; kc++) {
#pragma unroll
        for (int nt = 0; nt < 8; nt++) {
            const size_t woff = (size_t)(nt * 16 + l15) * 128 + kc * 32 + kq * 8;
            acc[nt] = __builtin_amdgcn_mfma_f32_16x16x32_bf16(
                xf[kc], *(const short8*)(Wr + woff), acc[nt], 0, 0, 0);
            acc[nt] = __builtin_amdgcn_mfma_f32_16x16x32_bf16(
                af[kc], *(const short8*)(Wl + woff), acc[nt], 0, 0, 0);
        }
    }

    if (LIN1) {
        // h1 = relu(acc+b) -> swizzled LDS (16-col blocks XORed by row>>2)
#pragma unroll
        for (int nt = 0; nt < 8; nt++) {
#pragma unroll
            for (int r = 0; r < 4; r++) {
                float v = fmaxf(acc[nt][r] + bcol[nt], 0.f);
                mybuf[(kq * 4 + r) * 128 + ((nt ^ kq) * 16 + l15)] = f2bf(v);
            }
        }
        short8 hf[4];
#pragma unroll
        for (int kc = 0; kc < 4; kc++) {
            int blk = kc * 2 + (kq >> 1);
            hf[kc] = *(const short8*)(mybuf + l15 * 128 +
                                      ((blk ^ (l15 >> 2)) * 16) + (kq & 1) * 8);
        }
#pragma unroll
        for (int nt = 0; nt < 8; nt++) {
            acc[nt] = (f32x4){0.f, 0.f, 0.f, 0.f};
            bcol[nt] = bias2[nt * 16 + l15];
        }
#pragma unroll
        for (int kc = 0; kc < 4; kc++) {
#pragma unroll
            for (int nt = 0; nt < 8; nt++) {
                const size_t woff = (size_t)(nt * 16 + l15) * 128 + kc * 32 + kq * 8;
                acc[nt] = __builtin_amdgcn_mfma_f32_16x16x32_bf16(
                    hf[kc], *(const short8*)(W2 + woff), acc[nt], 0, 0, 0);
            }
        }
    }

    if (POOL) {
        // fused global_mean_pool numerator (sums); counts handled in fc
        int rb = mw + kq * 4;
        int g[4];
#pragma unroll
        for (int r = 0; r < 4; r++) {
            int gr = rb + r;
            g[r] = (gr < N) ? (f64 ? batch[2 * gr] : batch[gr]) : -1;
        }
        bool same = (g[0] == g[1]) && (g[1] == g[2]) && (g[2] == g[3]) && (g[0] >= 0);
#pragma unroll
        for (int nt = 0; nt < 8; nt++) {
            int c = nt * 16 + l15;
            float v0 = fmaxf(acc[nt][0] + bcol[nt], 0.f);
            float v1 = fmaxf(acc[nt][1] + bcol[nt], 0.f);
            float v2 = fmaxf(acc[nt][2] + bcol[nt], 0.f);
            float v3 = fmaxf(acc[nt][3] + bcol[nt], 0.f);
            if (same) {
                int si = g[0] - gmin;
                float s4 = (v0 + v1) + (v2 + v3);
                if (si < 8) atomicAdd(&pbuf[si * 128 + c], s4);
                else        atomicAdd(&pool[g[0] * 128 + c], s4);
            } else {
                float vr[4] = {v0, v1, v2, v3};
#pragma unroll
                for (int r = 0; r < 4; r++) {
                    if (g[r] >= 0) {
                        int si = g[r] - gmin;
                        if (si < 8) atomicAdd(&pbuf[si * 128 + c], vr[r]);
                        else        atomicAdd(&pool[g[r] * 128 + c], vr[r]);
                    }
                }
            }
        }
        __syncthreads();
        for (int i = t; i < 1024; i += 256) {
            float v = pbuf[i];
            if (v != 0.f)
                atomicAdd(&pool[(gmin + (i >> 7)) * 128 + (i & 127)], v);
        }
    } else {
        // relu -> swizzled LDS -> coalesced bf16 store
#pragma unroll
        for (int nt = 0; nt < 8; nt++) {
#pragma unroll
            for (int r = 0; r < 4; r++) {
                float v = fmaxf(acc[nt][r] + bcol[nt], 0.f);
                mybuf[(kq * 4 + r) * 128 + ((nt ^ kq) * 16 + l15)] = f2bf(v);
            }
        }
#pragma unroll
        for (int p = 0; p < 4; p++) {
            int sidx = p * 512 + lane * 8;            // short index
            int row = sidx >> 7;                      // p*4 + (lane>>4)
            int colsh = sidx & 127;                   // (lane&15)*8
            int blk = colsh >> 4;
            int off = colsh & 15;
            int phys = row * 128 + ((blk ^ (row >> 2)) * 16) + off;
            int gm = mw + row;
            if (gm < N)
                *(uint4*)(Hdst + (size_t)gm * 128 + colsh) =
                    *(const uint4*)(mybuf + phys);
        }
    }
}

// ----- final fc (gstart inlined) -----------------------------------------
__global__ void fc_kernel(const float* __restrict__ pool,
                          const int* __restrict__ batch,
                          const float* __restrict__ W,
                          const float* __restrict__ b,
                          void* __restrict__ out,
                          const int* __restrict__ flags, int N, int G) {
    __shared__ int gst[64];
    int t = threadIdx.x;
    int f64 = flags[1];
    int isbf = flags[0];
    if (t <= G) {
        int lo = 0, hi = N;
        while (lo < hi) {
            int mid = (lo + hi) >> 1;
            int bv = f64 ? batch[2 * mid] : batch[mid];
            if (bv < t) lo = mid + 1; else hi = mid;
        }
        gst[t] = lo;
    }
    __syncthreads();
    if (t >= G * 3) return;
    int g = t / 3, o = t % 3;
    int cnt = gst[g + 1] - gst[g];
    float inv = 1.f / fmaxf((float)cnt, 1.f);
    float acc = 0.f;
    for (int k = 0; k < 128; k++)
        acc += pool[g * 128 + k] * W[o * 128 + k];
    float r = acc * inv + b[o];
    if (isbf) ((__hip_bfloat16*)out)[t] = __float2bfloat16(r);
    else      ((float*)out)[t] = r;
}

extern "C" void kernel_launch(void* const* d_in, const int* in_sizes, int n_in,
                              void* d_out, int out_size, void* d_ws, size_t ws_size,
                              hipStream_t stream) {
    const void* x   = d_in[0];
    const void* W0l = d_in[1];
    const void* b0l = d_in[2];
    const void* W0r = d_in[3];
    const void* W1  = d_in[4];
    const void* b1  = d_in[5];
    const void* W1l = d_in[6];
    const void* b1l = d_in[7];
    const void* W1r = d_in[8];
    const void* fcW = d_in[9];
    const void* fcb = d_in[10];
    const int* edge_index = (const int*)d_in[11];
    const int* batch      = (const int*)d_in[12];

    const int N = in_sizes[12];        // 50000
    const int E = in_sizes[11] / 2;    // 600000
    const int G = out_size / 3;        // 32

    char* ws = (char*)d_ws;
    auto align64 = [](size_t v) { return (v + 63) & ~(size_t)63; };
    size_t off = 0;
    size_t OFF_DEG  = off; off = align64(off + (size_t)N * 4);
    size_t OFF_POOL = off; off = align64(off + (size_t)G * 128 * 4);
    size_t MEMSET_BYTES = off;                  // deg + pool zeroed together
    size_t OFF_FLAGS = off; off = align64(off + 64);
    size_t OFF_ROWP = off; off = align64(off + (size_t)(N + 1) * 4);
    size_t OFF_WCUR = off; off = align64(off + (size_t)N * 4);
    size_t OFF_NBR  = off; off = align64(off + (size_t)E * 4);
    size_t OFF_WB   = off; off = align64(off + (size_t)WB_TOTAL * 2);
    size_t OFF_CF   = off; off = align64(off + (size_t)CF_TOTAL * 4);
    // +64 rows slack: MFMA X-frag tail reads past row N
    size_t OFF_HB   = off; off = align64(off + ((size_t)N + 64) * 128 * 2);
    size_t OFF_H2   = off; off = align64(off + ((size_t)N + 64) * 128 * 2);
    (void)ws_size;

    int*    deg    = (int*)(ws + OFF_DEG);
    float*  pool   = (float*)(ws + OFF_POOL);
    int*    flags  = (int*)(ws + OFF_FLAGS);
    int*    rowptr = (int*)(ws + OFF_ROWP);
    int*    wcur   = (int*)(ws + OFF_WCUR);
    int*    nbr    = (int*)(ws + OFF_NBR);
    unsigned short* wb = (unsigned short*)(ws + OFF_WB);
    float*  cf     = (float*)(ws + OFF_CF);
    unsigned short* Hb = (unsigned short*)(ws + OFF_HB);
    unsigned short* H2 = (unsigned short*)(ws + OFF_H2);

    hipMemsetAsync(ws, 0, MEMSET_BYTES, stream);

    probe_kernel<<<1, 256, 0, stream>>>((const unsigned short*)x, edge_index, flags);

    int n8 = (N * 128) / 8;
    cvt_kernel<<<(n8 + 255) / 256, 256, 0, stream>>>(x, Hb, flags, n8);
    wcvt_kernel<<<(WB_TOTAL + CF_TOTAL + 255) / 256, 256, 0, stream>>>(
        W0l, W0r, W1, W1l, W1r, b0l, b1, b1l, fcW, fcb, wb, cf, flags);

    int egrid = (E + 255) / 256;
    hist_kernel<<<egrid, 256, 0, stream>>>(edge_index, deg, flags, E);
    scan_kernel<<<1, 1024, 0, stream>>>(deg, rowptr, wcur, N);
    scatter_kernel<<<egrid, 256, 0, stream>>>(edge_index, wcur, nbr, flags, E);

    int cgrid = (N + 63) / 64;

    // conv0 + lin1 fused:  h2 = relu(relu(mean@W0l^T + x@W0r^T + b0l)@W1^T + b1)
    conv_kernel<true, false><<<cgrid, 256, 0, stream>>>(
        Hb, rowptr, nbr, wb + WB_W0L, wb + WB_W0R, cf + CF_B0L,
        wb + WB_W1, cf + CF_B1, H2, nullptr, nullptr, flags, N);

    // conv1 + pool fused:  pool += relu(mean(h2)@W1l^T + h2@W1r^T + b1l)
    conv_kernel<false, true><<<cgrid, 256, 0, stream>>>(
        H2, rowptr, nbr, wb + WB_W1L, wb + WB_W1R, cf + CF_B1L,
        nullptr, nullptr, nullptr, pool, batch, flags, N);

    fc_kernel<<<1, 128, 0, stream>>>(pool, batch, cf + CF_FCW, cf + CF_FCB,
                                     d_out, flags, N, G);

    (void)in_sizes; (void)n_in; (void)out_size;
}

// Round 5
// 312.050 us; speedup vs baseline: 3.3090x; 1.2731x over previous
//
#include <hip/hip_runtime.h>
#include <hip/hip_bf16.h>
#include <stdint.h>

// ---------------------------------------------------------------------------
// StaticGNN: SAGEConv(mean) -> ReLU -> Linear -> ReLU -> SAGEConv(mean) ->
//            ReLU -> global_mean_pool -> fc
// Round 5: 16 rows/block fused conv (3125 blocks, 4x TLP of round 4).
// Gather: quarter-wave per row (16B/lane), MLP-4 via shfl-broadcast indices.
// Matmul: 4 waves split 8 column tiles over shared LDS A-tile (padded 136
// shorts/row -> conflict-free b128 frag reads). lin1 fused (1 barrier),
// pool fused via block LDS buffer. prep_kernel fuses probe+cvt+wcvt+hist.
// ---------------------------------------------------------------------------

typedef __attribute__((ext_vector_type(8))) short short8;
typedef __attribute__((ext_vector_type(4))) float f32x4;

__device__ __forceinline__ float bits2f(uint32_t b) {
    union { uint32_t u; float f; } c; c.u = b; return c.f;
}
__device__ __forceinline__ unsigned short f2bf(float f) {
    __hip_bfloat16 h = __float2bfloat16(f);
    union { __hip_bfloat16 h; unsigned short u; } c; c.h = h; return c.u;
}
__device__ __forceinline__ uint32_t pack2bf(float a, float b) {
    return (uint32_t)f2bf(a) | ((uint32_t)f2bf(b) << 16);
}
__device__ __forceinline__ void acc8(float* a, uint4 v) {
    a[0] += bits2f(v.x << 16); a[1] += bits2f(v.x & 0xffff0000u);
    a[2] += bits2f(v.y << 16); a[3] += bits2f(v.y & 0xffff0000u);
    a[4] += bits2f(v.z << 16); a[5] += bits2f(v.z & 0xffff0000u);
    a[6] += bits2f(v.w << 16); a[7] += bits2f(v.w & 0xffff0000u);
}

// wave-local dtype detection (no cross-kernel dependency)
// isbf: float arrays are bf16; is64: int arrays are int64
__device__ __forceinline__ void detect_flags(const unsigned short* x,
                                             const int* ei,
                                             int& isbf, int& is64) {
    int lane = threadIdx.x & 63;
    unsigned short h = x[lane];
    int e = (h >> 7) & 0xFF;
    unsigned long long mbf = __ballot(e >= 102 && e <= 137);
    unsigned long long m64 = __ballot(ei[2 * lane + 1] != 0);
    isbf = (__popcll(mbf) >= 52) ? 1 : 0;
    is64 = (m64 == 0ULL) ? 1 : 0;
}

// ----- fused prep: flags + cvt(x->bf16 H) + wcvt + degree hist -----------
#define WB_W0L 0
#define WB_W0R 16384
#define WB_W1  32768
#define WB_W1L 49152
#define WB_W1R 65536
#define WB_TOTAL 81920
#define CF_B0L 0
#define CF_B1  128
#define CF_B1L 256
#define CF_FCW 384
#define CF_FCB 768
#define CF_TOTAL 771

__global__ __launch_bounds__(256) void prep_kernel(
    const void* x, const int* __restrict__ ei,
    const void* s0, const void* s1, const void* s2, const void* s3,
    const void* s4, const void* f0, const void* f1, const void* f2,
    const void* f3, const void* f4,
    unsigned short* __restrict__ Hb, unsigned short* __restrict__ wb,
    float* __restrict__ cf, int* __restrict__ deg, int* __restrict__ flags,
    int n8, int E, int CVT, int WC) {
    int isbf, is64;
    detect_flags((const unsigned short*)x, ei, isbf, is64);
    int b = blockIdx.x;
    if (b == 0 && threadIdx.x == 0) { flags[0] = isbf; flags[1] = is64; }

    if (b < CVT) {
        int i = b * 256 + threadIdx.x;
        if (i >= n8) return;
        uint4 d;
        if (isbf) {
            d = ((const uint4*)x)[i];
        } else {
            float4 a = ((const float4*)x)[2 * i];
            float4 c = ((const float4*)x)[2 * i + 1];
            d.x = pack2bf(a.x, a.y); d.y = pack2bf(a.z, a.w);
            d.z = pack2bf(c.x, c.y); d.w = pack2bf(c.z, c.w);
        }
        ((uint4*)Hb)[i] = d;
    } else if (b < CVT + WC) {
        int i = (b - CVT) * 256 + threadIdx.x;
        if (i < WB_TOTAL) {
            const void* p; int k = i & 16383;
            switch (i >> 14) {
                case 0: p = s0; break;
                case 1: p = s1; break;
                case 2: p = s2; break;
                case 3: p = s3; break;
                default: p = s4; break;
            }
            wb[i] = isbf ? ((const unsigned short*)p)[k]
                         : f2bf(((const float*)p)[k]);
        } else {
            int j = i - WB_TOTAL;
            if (j >= CF_TOTAL) return;
            const void* p; int k;
            if      (j < CF_B1)  { p = f0; k = j; }
            else if (j < CF_B1L) { p = f1; k = j - CF_B1; }
            else if (j < CF_FCW) { p = f2; k = j - CF_B1L; }
            else if (j < CF_FCB) { p = f3; k = j - CF_FCW; }
            else                 { p = f4; k = j - CF_FCB; }
            cf[j] = isbf ? bits2f((uint32_t)((const unsigned short*)p)[k] << 16)
                         : ((const float*)p)[k];
        }
    } else {
        int e = (b - CVT - WC) * 256 + threadIdx.x;
        if (e >= E) return;
        int d = is64 ? ei[2 * (E + e)] : ei[E + e];
        atomicAdd(&deg[d], 1);
    }
}

// ----- single-block exclusive scan (shuffle-based) -----------------------
__global__ __launch_bounds__(1024) void scan_kernel(
    const int* __restrict__ deg, int* __restrict__ rowptr,
    int* __restrict__ wcur, int n) {
    __shared__ int wsum[16];
    const int tid = threadIdx.x;
    const int lane = tid & 63, wid = tid >> 6;
    int running = 0;
    for (int base = 0; base < n; base += 4096) {
        int v[4]; int s = 0;
#pragma unroll
        for (int k = 0; k < 4; k++) {
            int i = base + tid * 4 + k;
            v[k] = (i < n) ? deg[i] : 0;
            s += v[k];
        }
        int sc = s;
#pragma unroll
        for (int off = 1; off < 64; off <<= 1) {
            int t = __shfl_up(sc, off, 64);
            if (lane >= off) sc += t;
        }
        if (lane == 63) wsum[wid] = sc;
        __syncthreads();
        int woff = 0, tot = 0;
        for (int w = 0; w < 16; w++) {
            int wv = wsum[w];
            tot += wv;
            if (w < wid) woff += wv;
        }
        int p = running + woff + (sc - s);
#pragma unroll
        for (int k = 0; k < 4; k++) {
            int i = base + tid * 4 + k;
            if (i < n) { rowptr[i] = p; wcur[i] = p; }
            p += v[k];
        }
        __syncthreads();
        running += tot;
    }
    if (tid == 0) rowptr[n] = running;
}

// ----- scatter src ids into CSR order ------------------------------------
__global__ __launch_bounds__(256) void scatter_kernel(
    const int* __restrict__ ei, int* __restrict__ wcur,
    int* __restrict__ nbr, const int* __restrict__ flags, int E) {
    int e = blockIdx.x * 256 + threadIdx.x;
    if (e >= E) return;
    int s, d;
    if (flags[1]) { s = ei[2 * e]; d = ei[2 * (E + e)]; }
    else          { s = ei[e];     d = ei[E + e]; }
    int pos = atomicAdd(&wcur[d], 1);
    nbr[pos] = s;
}

// ----- fused conv kernel: 16 rows/block, 4 waves -------------------------
// Phase1: quarter-wave per row gather-mean (4 rows/wave concurrent, MLP-4).
// Phase2: waves split 8 col-tiles (2 each) of MFMA over shared LDS A-tile.
// LIN1: relu -> LDS -> second MFMA (W2). POOL: fused segment pooling.
// LDS rows padded to 136 shorts (stride 68 dwords == 4 mod 32: no conflicts).
template <bool LIN1, bool POOL>
__global__ __launch_bounds__(256) void conv_kernel(
    const unsigned short* __restrict__ Hsrc,
    const int* __restrict__ rowptr, const int* __restrict__ nbr,
    const unsigned short* __restrict__ Wl, const unsigned short* __restrict__ Wr,
    const float* __restrict__ bias,
    const unsigned short* __restrict__ W2, const float* __restrict__ bias2,
    unsigned short* __restrict__ Hdst,
    float* __restrict__ pool, const int* __restrict__ batch,
    const int* __restrict__ flags, int N) {
    __shared__ unsigned short bufA[16 * 136];
    __shared__ unsigned short bufB[16 * 136];
    __shared__ float pbuf[4 * 128];
    const int t = threadIdx.x;
    const int lane = t & 63;
    const int w = t >> 6;
    const int l15 = lane & 15;
    const int kq = lane >> 4;
    const int m0 = blockIdx.x * 16;

    int f64 = 0, gmin = 0;
    if (POOL) {
        f64 = flags[1];
        gmin = f64 ? batch[2 * m0] : batch[m0];
        for (int i = t; i < 512; i += 256) pbuf[i] = 0.f;
    }

    // ---- phase 1: gather-mean; quarter kq of wave w handles row w*4+kq
    {
        const int row = w * 4 + kq;
        const int node = m0 + row;
        float a[8] = {0.f, 0.f, 0.f, 0.f, 0.f, 0.f, 0.f, 0.f};
        float invd = 0.f;
        if (node < N) {
            int s = rowptr[node], e = rowptr[node + 1];
            const uint4* H4 = (const uint4*)Hsrc;
            for (int base = s; base < e; base += 16) {
                int cnt = e - base; if (cnt > 16) cnt = 16;
                int idx = (l15 < cnt) ? nbr[base + l15] : 0;
                int it = 0;
                for (; it + 4 <= cnt; it += 4) {
                    int j0 = __shfl(idx, kq * 16 + it, 64);
                    int j1 = __shfl(idx, kq * 16 + it + 1, 64);
                    int j2 = __shfl(idx, kq * 16 + it + 2, 64);
                    int j3 = __shfl(idx, kq * 16 + it + 3, 64);
                    uint4 v0 = H4[(size_t)j0 * 16 + l15];
                    uint4 v1 = H4[(size_t)j1 * 16 + l15];
                    uint4 v2 = H4[(size_t)j2 * 16 + l15];
                    uint4 v3 = H4[(size_t)j3 * 16 + l15];
                    acc8(a, v0); acc8(a, v1); acc8(a, v2); acc8(a, v3);
                }
                for (; it < cnt; ++it) {
                    int j = __shfl(idx, kq * 16 + it, 64);
                    acc8(a, H4[(size_t)j * 16 + l15]);
                }
            }
            invd = 1.f / fmaxf((float)(e - s), 1.f);
        }
        uint4 o;
        o.x = pack2bf(a[0] * invd, a[1] * invd);
        o.y = pack2bf(a[2] * invd, a[3] * invd);
        o.z = pack2bf(a[4] * invd, a[5] * invd);
        o.w = pack2bf(a[6] * invd, a[7] * invd);
        *(uint4*)(bufA + row * 136 + l15 * 8) = o;
    }
    __syncthreads();

    // ---- phase 2: MFMA; wave w owns col tiles nt0, nt0+1
    const int nt0 = w * 2;
    short8 af[4], xf[4];
    {
        const unsigned short* xrow = Hsrc + (size_t)(m0 + l15) * 128 + kq * 8;
#pragma unroll
        for (int kc = 0; kc < 4; kc++) {
            af[kc] = *(const short8*)(bufA + l15 * 136 + kc * 32 + kq * 8);
            xf[kc] = *(const short8*)(xrow + kc * 32);
        }
    }
    f32x4 acc[2];
    acc[0] = (f32x4){0.f, 0.f, 0.f, 0.f};
    acc[1] = (f32x4){0.f, 0.f, 0.f, 0.f};
    float bc[2] = {bias[nt0 * 16 + l15], bias[(nt0 + 1) * 16 + l15]};
#pragma unroll
    for (int kc = 0; kc < 4; kc++) {
#pragma unroll
        for (int u = 0; u < 2; u++) {
            const size_t woff = (size_t)((nt0 + u) * 16 + l15) * 128 + kc * 32 + kq * 8;
            acc[u] = __builtin_amdgcn_mfma_f32_16x16x32_bf16(
                xf[kc], *(const short8*)(Wr + woff), acc[u], 0, 0, 0);
            acc[u] = __builtin_amdgcn_mfma_f32_16x16x32_bf16(
                af[kc], *(const short8*)(Wl + woff), acc[u], 0, 0, 0);
        }
    }

    if (LIN1) {
        // h1 = relu(acc+b) -> bufB (each wave writes its own cols)
#pragma unroll
        for (int u = 0; u < 2; u++) {
#pragma unroll
            for (int r = 0; r < 4; r++) {
                bufB[(kq * 4 + r) * 136 + (nt0 + u) * 16 + l15] =
                    f2bf(fmaxf(acc[u][r] + bc[u], 0.f));
            }
        }
        __syncthreads();
        short8 hf[4];
#pragma unroll
        for (int kc = 0; kc < 4; kc++)
            hf[kc] = *(const short8*)(bufB + l15 * 136 + kc * 32 + kq * 8);
        acc[0] = (f32x4){0.f, 0.f, 0.f, 0.f};
        acc[1] = (f32x4){0.f, 0.f, 0.f, 0.f};
        bc[0] = bias2[nt0 * 16 + l15];
        bc[1] = bias2[(nt0 + 1) * 16 + l15];
#pragma unroll
        for (int kc = 0; kc < 4; kc++) {
#pragma unroll
            for (int u = 0; u < 2; u++) {
                const size_t woff = (size_t)((nt0 + u) * 16 + l15) * 128 + kc * 32 + kq * 8;
                acc[u] = __builtin_amdgcn_mfma_f32_16x16x32_bf16(
                    hf[kc], *(const short8*)(W2 + woff), acc[u], 0, 0, 0);
            }
        }
    }

    if (POOL) {
        int g[4];
#pragma unroll
        for (int r = 0; r < 4; r++) {
            int gr = m0 + kq * 4 + r;
            g[r] = (gr < N) ? (f64 ? batch[2 * gr] : batch[gr]) : -1;
        }
        bool same = (g[0] == g[1]) && (g[1] == g[2]) && (g[2] == g[3]) && (g[0] >= 0);
#pragma unroll
        for (int u = 0; u < 2; u++) {
            int c = (nt0 + u) * 16 + l15;
            float v0 = fmaxf(acc[u][0] + bc[u], 0.f);
            float v1 = fmaxf(acc[u][1] + bc[u], 0.f);
            float v2 = fmaxf(acc[u][2] + bc[u], 0.f);
            float v3 = fmaxf(acc[u][3] + bc[u], 0.f);
            if (same) {
                int si = g[0] - gmin;
                float s4 = (v0 + v1) + (v2 + v3);
                if (si < 4) atomicAdd(&pbuf[si * 128 + c], s4);
                else        atomicAdd(&pool[g[0] * 128 + c], s4);
            } else {
                float vr[4] = {v0, v1, v2, v3};
#pragma unroll
                for (int r = 0; r < 4; r++) {
                    if (g[r] >= 0) {
                        int si = g[r] - gmin;
                        if (si < 4) atomicAdd(&pbuf[si * 128 + c], vr[r]);
                        else        atomicAdd(&pool[g[r] * 128 + c], vr[r]);
                    }
                }
            }
        }
        __syncthreads();
        for (int i = t; i < 512; i += 256) {
            float v = pbuf[i];
            if (v != 0.f)
                atomicAdd(&pool[(gmin + (i >> 7)) * 128 + (i & 127)], v);
        }
    } else {
        // stage C-layout into bufA (free after frag reads), coalesced store
#pragma unroll
        for (int u = 0; u < 2; u++) {
#pragma unroll
            for (int r = 0; r < 4; r++) {
                bufA[(kq * 4 + r) * 136 + (nt0 + u) * 16 + l15] =
                    f2bf(fmaxf(acc[u][r] + bc[u], 0.f));
            }
        }
        __syncthreads();
        int row = t >> 4, colsh = (t & 15) * 8;
        uint4 val = *(const uint4*)(bufA + row * 136 + colsh);
        if (m0 + row < N)
            *(uint4*)(Hdst + (size_t)(m0 + row) * 128 + colsh) = val;
    }
}

// ----- final fc (gstart inlined) -----------------------------------------
__global__ void fc_kernel(const float* __restrict__ pool,
                          const int* __restrict__ batch,
                          const float* __restrict__ W,
                          const float* __restrict__ b,
                          void* __restrict__ out,
                          const int* __restrict__ flags, int N, int G) {
    __shared__ int gst[64];
    int t = threadIdx.x;
    int f64 = flags[1];
    int isbf = flags[0];
    if (t <= G) {
        int lo = 0, hi = N;
        while (lo < hi) {
            int mid = (lo + hi) >> 1;
            int bv = f64 ? batch[2 * mid] : batch[mid];
            if (bv < t) lo = mid + 1; else hi = mid;
        }
        gst[t] = lo;
    }
    __syncthreads();
    if (t >= G * 3) return;
    int g = t / 3, o = t % 3;
    int cnt = gst[g + 1] - gst[g];
    float inv = 1.f / fmaxf((float)cnt, 1.f);
    float acc = 0.f;
    for (int k = 0; k < 128; k++)
        acc += pool[g * 128 + k] * W[o * 128 + k];
    float r = acc * inv + b[o];
    if (isbf) ((__hip_bfloat16*)out)[t] = __float2bfloat16(r);
    else      ((float*)out)[t] = r;
}

extern "C" void kernel_launch(void* const* d_in, const int* in_sizes, int n_in,
                              void* d_out, int out_size, void* d_ws, size_t ws_size,
                              hipStream_t stream) {
    const void* x   = d_in[0];
    const void* W0l = d_in[1];
    const void* b0l = d_in[2];
    const void* W0r = d_in[3];
    const void* W1  = d_in[4];
    const void* b1  = d_in[5];
    const void* W1l = d_in[6];
    const void* b1l = d_in[7];
    const void* W1r = d_in[8];
    const void* fcW = d_in[9];
    const void* fcb = d_in[10];
    const int* edge_index = (const int*)d_in[11];
    const int* batch      = (const int*)d_in[12];

    const int N = in_sizes[12];        // 50000
    const int E = in_sizes[11] / 2;    // 600000
    const int G = out_size / 3;        // 32

    char* ws = (char*)d_ws;
    auto align64 = [](size_t v) { return (v + 63) & ~(size_t)63; };
    size_t off = 0;
    size_t OFF_DEG  = off; off = align64(off + (size_t)N * 4);
    size_t OFF_POOL = off; off = align64(off + (size_t)G * 128 * 4);
    size_t MEMSET_BYTES = off;                  // deg + pool zeroed together
    size_t OFF_FLAGS = off; off = align64(off + 64);
    size_t OFF_ROWP = off; off = align64(off + (size_t)(N + 1) * 4);
    size_t OFF_WCUR = off; off = align64(off + (size_t)N * 4);
    size_t OFF_NBR  = off; off = align64(off + (size_t)E * 4);
    size_t OFF_WB   = off; off = align64(off + (size_t)WB_TOTAL * 2);
    size_t OFF_CF   = off; off = align64(off + (size_t)CF_TOTAL * 4);
    // +64 rows slack: MFMA X-frag tail reads past row N
    size_t OFF_HB   = off; off = align64(off + ((size_t)N + 64) * 128 * 2);
    size_t OFF_H2   = off; off = align64(off + ((size_t)N + 64) * 128 * 2);
    (void)ws_size;

    int*    deg    = (int*)(ws + OFF_DEG);
    float*  pool   = (float*)(ws + OFF_POOL);
    int*    flags  = (int*)(ws + OFF_FLAGS);
    int*    rowptr = (int*)(ws + OFF_ROWP);
    int*    wcur   = (int*)(ws + OFF_WCUR);
    int*    nbr    = (int*)(ws + OFF_NBR);
    unsigned short* wb = (unsigned short*)(ws + OFF_WB);
    float*  cf     = (float*)(ws + OFF_CF);
    unsigned short* Hb = (unsigned short*)(ws + OFF_HB);
    unsigned short* H2 = (unsigned short*)(ws + OFF_H2);

    hipMemsetAsync(ws, 0, MEMSET_BYTES, stream);

    int n8 = (N * 128) / 8;
    int CVT = (n8 + 255) / 256;
    int WC  = (WB_TOTAL + CF_TOTAL + 255) / 256;
    int HG  = (E + 255) / 256;
    prep_kernel<<<CVT + WC + HG, 256, 0, stream>>>(
        x, edge_index, W0l, W0r, W1, W1l, W1r, b0l, b1, b1l, fcW, fcb,
        Hb, wb, cf, deg, flags, n8, E, CVT, WC);

    scan_kernel<<<1, 1024, 0, stream>>>(deg, rowptr, wcur, N);
    scatter_kernel<<<HG, 256, 0, stream>>>(edge_index, wcur, nbr, flags, E);

    int cgrid = (N + 15) / 16;

    // conv0 + lin1 fused:  h2 = relu(relu(mean@W0l^T + x@W0r^T + b0l)@W1^T + b1)
    conv_kernel<true, false><<<cgrid, 256, 0, stream>>>(
        Hb, rowptr, nbr, wb + WB_W0L, wb + WB_W0R, cf + CF_B0L,
        wb + WB_W1, cf + CF_B1, H2, nullptr, nullptr, flags, N);

    // conv1 + pool fused:  pool += relu(mean(h2)@W1l^T + h2@W1r^T + b1l)
    conv_kernel<false, true><<<cgrid, 256, 0, stream>>>(
        H2, rowptr, nbr, wb + WB_W1L, wb + WB_W1R, cf + CF_B1L,
        nullptr, nullptr, nullptr, pool, batch, flags, N);

    fc_kernel<<<1, 128, 0, stream>>>(pool, batch, cf + CF_FCW, cf + CF_FCB,
                                     d_out, flags, N, G);

    (void)in_sizes; (void)n_in; (void)out_size;
}